// Round 7
// baseline (196.109 us; speedup 1.0000x reference)
//
#include <hip/hip_runtime.h>
#include <math.h>

#define NANCH 896
#define MAXD 64
#define NS 14   // 896 / 64 max slots per lane

// Templated NMS: NSLOT compile-time (straight-line hot scans, R5-proven).
// Round-6/7: DEFERRED EPILOGUE. Phase A (serial loop) does ONLY selection and
// removal, writing each row's raw {acc[16], score, wsum} to an LDS row buffer
// with fire-and-forget stores. Phase B (after the loop, once) does the
// reduce-read/divide/project/store for all 64 rows in parallel. The blend
// transpose + divide + project + store leave the serial critical path.
template <int NSLOT>
__device__ __forceinline__ void nms_loop(
    const int lane, const int nact,
    const float4* __restrict__ cbox, const float* __restrict__ cscore,
    const unsigned short* __restrict__ cidx, float* __restrict__ rowbuf,
    const float* __restrict__ rb, const float* __restrict__ anchors,
    const float m0, const float m1, const float m3,
    const float m4, const float m5, const float m7,
    const float hf, const float wf, float* __restrict__ ob)
{
    const float inv = 1.f / 128.f;

    // ---- readback compacted entries into registers. MUST complete before
    //      any rowbuf write: rowbuf aliases cscore/cidx (same-wave in-order
    //      program order guarantees this). ----
    float cb0[NSLOT], cb1[NSLOT], cb2[NSLOT], cb3[NSLOT], car[NSLOT], rem[NSLOT];
    int   corig[NSLOT];
#pragma unroll
    for (int k = 0; k < NSLOT; ++k) {
        int p = k * 64 + lane;
        bool v = (p < nact);
        int pc = v ? p : 0;
        float4 bb = cbox[pc];
        cb0[k] = bb.x; cb1[k] = bb.y; cb2[k] = bb.z; cb3[k] = bb.w;
        car[k] = fmaxf(bb.z - bb.x, 0.f) * fmaxf(bb.w - bb.y, 0.f);
        corig[k] = (int)cidx[pc];
        rem[k] = v ? cscore[pc] : -1.f;
    }

    // ================= Phase A: serial selection loop =================
    int nrows; bool stuckmode = false;
    int iter = 0;
    while (true) {
        // ---- argmax(rem), first-compacted-pos tie-break (proven) ----
        float bv = -2.f; int bi = 1 << 30;
#pragma unroll
        for (int j = 0; j < NSLOT; ++j) {
            if (rem[j] > bv) { bv = rem[j]; bi = j * 64 + lane; }
        }
#pragma unroll
        for (int s2 = 32; s2 >= 1; s2 >>= 1) {
            float ov = __shfl_xor(bv, s2, 64);
            int   oi = __shfl_xor(bi, s2, 64);
            if (ov > bv || (ov == bv && oi < bi)) { bv = ov; bi = oi; }
        }

        if (bv <= 0.f) { nrows = iter; break; }        // exhausted -> zero rows

        // ---- best box: one broadcast LDS read (uniform address) ----
        float4 bb = cbox[bi];
        const float bby0 = bb.x, bbx0 = bb.y, bby1 = bb.z, bbx1 = bb.w;
        const float a1 = fmaxf(bby1 - bby0, 0.f) * fmaxf(bbx1 - bbx0, 0.f);

        float acc[16];
#pragma unroll
        for (int c = 0; c < 16; ++c) acc[c] = 0.f;
        float wsum = 0.f;
        bool anyov = false;

        // ---- overlap scan (straight-line, proven arithmetic/order) ----
#pragma unroll
        for (int j = 0; j < NSLOT; ++j) {
            float yA = fmaxf(bby0, cb0[j]);
            float xA = fmaxf(bbx0, cb1[j]);
            float yB = fminf(bby1, cb2[j]);
            float xB = fminf(bbx1, cb3[j]);
            float inter = fmaxf(yB - yA, 0.f) * fmaxf(xB - xA, 0.f);
            if (inter > 0.f) {
                float iou = inter / fmaxf(a1 + car[j] - inter, 1e-6f);
                if (iou > 0.3f && rem[j] > 0.f) {
                    anyov = true;
                    float wj = rem[j];          // rem>0 ==> rem == score
                    rem[j] = -1.f;
                    wsum += wj;
                    acc[0] += cb0[j] * wj; acc[1] += cb1[j] * wj;
                    acc[2] += cb2[j] * wj; acc[3] += cb3[j] * wj;
                    const int orig = corig[j];
                    float4 an = *(const float4*)(anchors + orig * 4);
                    const float* rp = rb + orig * 16;
                    float4 r1 = *(const float4*)(rp + 4);
                    float4 r2 = *(const float4*)(rp + 8);
                    float4 r3 = *(const float4*)(rp + 12);
                    acc[4]  += (r1.x * inv * an.z + an.x) * wj;
                    acc[5]  += (r1.y * inv * an.w + an.y) * wj;
                    acc[6]  += (r1.z * inv * an.z + an.x) * wj;
                    acc[7]  += (r1.w * inv * an.w + an.y) * wj;
                    acc[8]  += (r2.x * inv * an.z + an.x) * wj;
                    acc[9]  += (r2.y * inv * an.w + an.y) * wj;
                    acc[10] += (r2.z * inv * an.z + an.x) * wj;
                    acc[11] += (r2.w * inv * an.w + an.y) * wj;
                    acc[12] += (r3.x * inv * an.z + an.x) * wj;
                    acc[13] += (r3.y * inv * an.w + an.y) * wj;
                    acc[14] += (r3.z * inv * an.z + an.x) * wj;
                    acc[15] += (r3.w * inv * an.w + an.y) * wj;
                }
            }
        }

        const unsigned long long mm = __ballot(anyov);
        float* rowp = rowbuf + iter * 20;              // stride 20 -> 16B-aligned

        if (mm == 0ull) {                              // stuck fixed point
            if (lane == 0) {
                *(float4*)(rowp +  0) = make_float4(0.f, 0.f, 0.f, 0.f);
                *(float4*)(rowp +  4) = make_float4(0.f, 0.f, 0.f, 0.f);
                *(float4*)(rowp +  8) = make_float4(0.f, 0.f, 0.f, 0.f);
                *(float4*)(rowp + 12) = make_float4(0.f, 0.f, 0.f, 0.f);
                rowp[16] = bv; rowp[17] = 0.f;
            }
            nrows = iter; stuckmode = true; break;
        }
        if (__popcll(mm) == 1) {
            // FAST PATH: single contributor -> its registers ARE the totals
            // (all other lanes hold +0). Fire-and-forget LDS stores only.
            const int src = (int)__ffsll((long long)mm) - 1;
            if (lane == src) {
                *(float4*)(rowp +  0) = make_float4(acc[0],  acc[1],  acc[2],  acc[3]);
                *(float4*)(rowp +  4) = make_float4(acc[4],  acc[5],  acc[6],  acc[7]);
                *(float4*)(rowp +  8) = make_float4(acc[8],  acc[9],  acc[10], acc[11]);
                *(float4*)(rowp + 12) = make_float4(acc[12], acc[13], acc[14], acc[15]);
                rowp[16] = bv; rowp[17] = wsum;
            }
        } else {
            // general path (rare): identical butterfly tree as proven rounds
#pragma unroll
            for (int s2 = 32; s2 >= 1; s2 >>= 1) {
                wsum += __shfl_xor(wsum, s2, 64);
#pragma unroll
                for (int c = 0; c < 16; ++c) acc[c] += __shfl_xor(acc[c], s2, 64);
            }
            if (lane == 0) {
                *(float4*)(rowp +  0) = make_float4(acc[0],  acc[1],  acc[2],  acc[3]);
                *(float4*)(rowp +  4) = make_float4(acc[4],  acc[5],  acc[6],  acc[7]);
                *(float4*)(rowp +  8) = make_float4(acc[8],  acc[9],  acc[10], acc[11]);
                *(float4*)(rowp + 12) = make_float4(acc[12], acc[13], acc[14], acc[15]);
                rowp[16] = bv; rowp[17] = wsum;
            }
        }
        ++iter;
        if (iter == MAXD) { nrows = MAXD; break; }
    }

    // ================= Phase B: parallel epilogue (once) =================
    // Same math as the proven R5 epilogue; totals round-trip LDS bit-exactly.
    const bool isx = (lane < 16) && ((0x555Au >> lane) & 1u);
#pragma unroll 4
    for (int r = 0; r < MAXD; ++r) {
        const int sr = (r < nrows) ? r : (stuckmode ? nrows : -1);
        float detc = 0.f;
        if (sr >= 0) {                                 // wave-uniform branch
            const float* rowp = rowbuf + sr * 20;
            const float tv  = rowp[lane & 15];         // multicast-friendly
            const float scv = rowp[16];                // uniform broadcast
            const float wsv = rowp[17];                // uniform broadcast
            const float dnm = fmaxf(wsv, 1e-6f);
            float q = tv / dnm;                        // ONE divide per lane
            const float p = __shfl(q, lane ^ 1, 64);   // x/y partner channel
            detc = (lane >= 16) ? scv
                 : (isx ? (q * m0 + p * m1 + m3) * wf
                        : (p * m4 + q * m5 + m7) * hf);
        }
        if (lane < 17) ob[r * 17 + lane] = detc;
    }
}

// ONE WAVE per batch. Setup (loads, sigmoid, decode, compaction) identical to
// the proven R4/R5 kernel. The row buffer ALIASES cscore/cidx (dead after the
// register readback) so LDS stays 19712 B -> 8 blocks/CU preserved.
__global__ __launch_bounds__(64, 2) void blaze_wave_kernel(
    const float* __restrict__ raw_boxes,   // [B,896,16]
    const float* __restrict__ raw_scores,  // [B,896]
    const float* __restrict__ anchors,     // [896,4]
    const float* __restrict__ tmat,        // [B,8]
    const int* __restrict__ hptr,
    const int* __restrict__ wptr,
    float* __restrict__ out,               // [B,64,17]
    int B)
{
    __shared__ float4 cbox[NANCH];                         // 14336 B
    __shared__ __align__(16) unsigned char upool[5376];    // union region
    float*          cscore = (float*)upool;                // [896] floats
    unsigned short* cidx   = (unsigned short*)(upool + 3584); // [896] u16
    float*          rowbuf = (float*)upool;                // [64*20] floats

    const int lane = threadIdx.x;             // 0..63
    const int b    = blockIdx.x;
    if (b >= B) return;

    const float* rb = raw_boxes  + (size_t)b * (NANCH * 16);
    const float* rs = raw_scores + (size_t)b * NANCH;
    const float inv = 1.f / 128.f;

    // ---- uniform per-batch params in the up-front load burst ----
    const float* M = tmat + (size_t)b * 8;
    const float m0 = M[0], m1 = M[1], m3 = M[3];
    const float m4 = M[4], m5 = M[5], m7 = M[7];
    const float hf = (float)(*hptr);
    const float wf = (float)(*wptr);

    // ---- Phase 1: ALL score loads issued back-to-back ----
    float xv[NS];
#pragma unroll
    for (int j = 0; j < NS; ++j) xv[j] = rs[lane + 64 * j];

    // ---- Phase 2: box/anchor loads gated by SIGN only (sigmoid>=0.5 <=> x>=0;
    //      NaN -> inactive both sides). Inactive lanes alias row 0's line. ----
    bool  act[NS];
    float4 r0v[NS], anv[NS];
#pragma unroll
    for (int j = 0; j < NS; ++j) {
        act[j] = (xv[j] >= 0.f);
        const int a2 = act[j] ? (lane + 64 * j) : 0;
        r0v[j] = *(const float4*)(rb + a2 * 16);
        anv[j] = *(const float4*)(anchors + a2 * 4);
    }

    // ---- sigmoid overlaps the in-flight box loads ----
    float sv[NS];
#pragma unroll
    for (int j = 0; j < NS; ++j) {
        float x = fminf(fmaxf(xv[j], -100.f), 100.f);
        sv[j] = 1.f / (1.f + expf(-x));
    }

    // ---- decode + COMPACT active anchors into LDS (ascending anchor order:
    //      compacted pos is order-isomorphic to anchor index -> exact tiebreak) ----
    int base = 0;
#pragma unroll
    for (int j = 0; j < NS; ++j) {
        float xc = r0v[j].x * inv * anv[j].z + anv[j].x;
        float yc = r0v[j].y * inv * anv[j].w + anv[j].y;
        float ww = r0v[j].z * inv * anv[j].z;
        float hh = r0v[j].w * inv * anv[j].w;
        float y0 = yc - hh * 0.5f, x0 = xc - ww * 0.5f;
        float y1 = yc + hh * 0.5f, x1 = xc + ww * 0.5f;
        unsigned long long m = __ballot(act[j]);
        int pos = base + __popcll(m & ((1ull << lane) - 1ull));
        if (act[j]) {
            cbox[pos]   = make_float4(y0, x0, y1, x1);
            cscore[pos] = sv[j];
            cidx[pos]   = (unsigned short)(lane + 64 * j);
        }
        base += __popcll(m);
    }
    const int nact = base;                  // wave-uniform
    const int nsc  = (nact + 63) >> 6;      // wave-uniform active slot count

    float* ob = out + (size_t)b * (MAXD * 17);

    // ---- one wave-uniform dispatch to a compile-time slot count ----
    if (nsc <= 7)
        nms_loop<7>(lane, nact, cbox, cscore, cidx, rowbuf, rb, anchors,
                    m0, m1, m3, m4, m5, m7, hf, wf, ob);
    else if (nsc <= 8)
        nms_loop<8>(lane, nact, cbox, cscore, cidx, rowbuf, rb, anchors,
                    m0, m1, m3, m4, m5, m7, hf, wf, ob);
    else if (nsc <= 10)
        nms_loop<10>(lane, nact, cbox, cscore, cidx, rowbuf, rb, anchors,
                     m0, m1, m3, m4, m5, m7, hf, wf, ob);
    else
        nms_loop<14>(lane, nact, cbox, cscore, cidx, rowbuf, rb, anchors,
                     m0, m1, m3, m4, m5, m7, hf, wf, ob);
}

extern "C" void kernel_launch(void* const* d_in, const int* in_sizes, int n_in,
                              void* d_out, int out_size, void* d_ws, size_t ws_size,
                              hipStream_t stream) {
    (void)n_in; (void)out_size; (void)d_ws; (void)ws_size;
    const float* raw_boxes  = (const float*)d_in[0];
    const float* raw_scores = (const float*)d_in[1];
    const float* anchors    = (const float*)d_in[2];
    const float* tmat       = (const float*)d_in[3];
    const int*   hptr       = (const int*)d_in[4];
    const int*   wptr       = (const int*)d_in[5];
    float* out = (float*)d_out;

    const int B = in_sizes[0] / (NANCH * 16);
    blaze_wave_kernel<<<B, 64, 0, stream>>>(raw_boxes, raw_scores, anchors,
                                            tmat, hptr, wptr, out, B);
}

// Round 8
// 188.868 us; speedup vs baseline: 1.0383x; 1.0383x over previous
//
#include <hip/hip_runtime.h>
#include <math.h>

#define NANCH 896
#define MAXD 64
#define NS 14   // 896 / 64 max slots per lane

// Templated NMS: NSLOT compile-time (straight-line hot scans, R5-proven).
// Round-8 = R5 verbatim + ONE change: EARLY-ISSUE of the best box's
// keypoint/anchor loads right after argmax. The best box contributes every
// non-stuck iteration (self-IoU = 1), and its loads were previously issued
// mid-scan and consumed immediately -> ~200-400 cyc vmcnt stall per
// iteration at L3 latency. Issuing them before the cbox broadcast + IoU scan
// hides that latency under ~200 cyc of independent work.
template <int NSLOT>
__device__ __forceinline__ void nms_loop(
    const int lane, const int nact,
    const float4* __restrict__ cbox, const float* __restrict__ cscore,
    const unsigned short* __restrict__ cidx, float* __restrict__ sdet,
    const float* __restrict__ rb, const float* __restrict__ anchors,
    const float m0, const float m1, const float m3,
    const float m4, const float m5, const float m7,
    const float hf, const float wf, float* __restrict__ ob)
{
    const float inv = 1.f / 128.f;

    // ---- readback compacted entries into per-lane slot registers ----
    float cb0[NSLOT], cb1[NSLOT], cb2[NSLOT], cb3[NSLOT], car[NSLOT], rem[NSLOT];
    int   corig[NSLOT];
#pragma unroll
    for (int k = 0; k < NSLOT; ++k) {
        int p = k * 64 + lane;
        bool v = (p < nact);
        int pc = v ? p : 0;
        float4 bb = cbox[pc];
        cb0[k] = bb.x; cb1[k] = bb.y; cb2[k] = bb.z; cb3[k] = bb.w;
        car[k] = fmaxf(bb.z - bb.x, 0.f) * fmaxf(bb.w - bb.y, 0.f);
        corig[k] = (int)cidx[pc];
        rem[k] = v ? cscore[pc] : -1.f;
    }

    // x-channels: {1,3,4,6,8,10,12,14} -> bitmask 0x555A; partner = c^1
    const bool isx = (lane < 16) && ((0x555Au >> lane) & 1u);

    int iter = 0;
    while (true) {
        // ---- argmax(rem), first-compacted-pos tie-break (proven) ----
        float bv = -2.f; int bi = 1 << 30;
#pragma unroll
        for (int j = 0; j < NSLOT; ++j) {
            if (rem[j] > bv) { bv = rem[j]; bi = j * 64 + lane; }
        }
#pragma unroll
        for (int s2 = 32; s2 >= 1; s2 >>= 1) {
            float ov = __shfl_xor(bv, s2, 64);
            int   oi = __shfl_xor(bi, s2, 64);
            if (ov > bv || (ov == bv && oi < bi)) { bv = ov; bi = oi; }
        }

        if (bv <= 0.f) {                    // nothing active left -> zero fill
            int n = (MAXD - iter) * 17;
            float* op = ob + iter * 17;
            for (int e = lane; e < n; e += 64) op[e] = 0.f;
            break;
        }

        const int bl = bi & 63, bj = bi >> 6;

        // ---- EARLY ISSUE: best-box keypoint/anchor loads. orig at runtime
        //      slot bj selected via unrolled cndmask (no runtime reg-indexing).
        //      Only lane bl's value is meaningful; only lane bl loads. ----
        int orig_b = corig[0];
#pragma unroll
        for (int k = 1; k < NSLOT; ++k) orig_b = (bj == k) ? corig[k] : orig_b;
        float4 pre_an = make_float4(0.f, 0.f, 0.f, 0.f);
        float4 pre_r1 = pre_an, pre_r2 = pre_an, pre_r3 = pre_an;
        if (lane == bl) {
            const float* rp = rb + orig_b * 16;
            pre_an = *(const float4*)(anchors + orig_b * 4);
            pre_r1 = *(const float4*)(rp + 4);
            pre_r2 = *(const float4*)(rp + 8);
            pre_r3 = *(const float4*)(rp + 12);
        }

        // ---- best box: one broadcast LDS read (uniform address) ----
        float4 bb = cbox[bi];
        const float bby0 = bb.x, bbx0 = bb.y, bby1 = bb.z, bbx1 = bb.w;
        const float a1 = fmaxf(bby1 - bby0, 0.f) * fmaxf(bbx1 - bbx0, 0.f);

        float acc[16];
#pragma unroll
        for (int c = 0; c < 16; ++c) acc[c] = 0.f;
        float wsum = 0.f;
        bool anyov = false;

        // ---- overlap scan (straight-line, proven arithmetic/order) ----
#pragma unroll
        for (int j = 0; j < NSLOT; ++j) {
            float yA = fmaxf(bby0, cb0[j]);
            float xA = fmaxf(bbx0, cb1[j]);
            float yB = fminf(bby1, cb2[j]);
            float xB = fminf(bbx1, cb3[j]);
            float inter = fmaxf(yB - yA, 0.f) * fmaxf(xB - xA, 0.f);
            if (inter > 0.f) {
                float iou = inter / fmaxf(a1 + car[j] - inter, 1e-6f);
                if (iou > 0.3f && rem[j] > 0.f) {
                    anyov = true;
                    float wj = rem[j];          // rem>0 ==> rem == score
                    rem[j] = -1.f;
                    wsum += wj;
                    acc[0] += cb0[j] * wj; acc[1] += cb1[j] * wj;
                    acc[2] += cb2[j] * wj; acc[3] += cb3[j] * wj;
                    // keypoints: best-box lane uses the preloaded registers
                    // (same addresses -> identical values); others load here.
                    float4 an, r1, r2, r3;
                    if ((lane == bl) && (j == bj)) {
                        an = pre_an; r1 = pre_r1; r2 = pre_r2; r3 = pre_r3;
                    } else {
                        const int orig = corig[j];
                        const float* rp = rb + orig * 16;
                        an = *(const float4*)(anchors + orig * 4);
                        r1 = *(const float4*)(rp + 4);
                        r2 = *(const float4*)(rp + 8);
                        r3 = *(const float4*)(rp + 12);
                    }
                    acc[4]  += (r1.x * inv * an.z + an.x) * wj;
                    acc[5]  += (r1.y * inv * an.w + an.y) * wj;
                    acc[6]  += (r1.z * inv * an.z + an.x) * wj;
                    acc[7]  += (r1.w * inv * an.w + an.y) * wj;
                    acc[8]  += (r2.x * inv * an.z + an.x) * wj;
                    acc[9]  += (r2.y * inv * an.w + an.y) * wj;
                    acc[10] += (r2.z * inv * an.z + an.x) * wj;
                    acc[11] += (r2.w * inv * an.w + an.y) * wj;
                    acc[12] += (r3.x * inv * an.z + an.x) * wj;
                    acc[13] += (r3.y * inv * an.w + an.y) * wj;
                    acc[14] += (r3.z * inv * an.z + an.x) * wj;
                    acc[15] += (r3.w * inv * an.w + an.y) * wj;
                }
            }
        }

        const unsigned long long mm = __ballot(anyov);
        const bool stuck = (mm == 0ull);

        float q, dnm;
        if (stuck) {
            q = 0.f; dnm = 1e-6f;            // reference: blend of zeros
        } else if (__popcll(mm) == 1) {
            // FAST PATH: one contributing lane -> broadcast its partials.
            // Bit-exact vs butterfly: all other lanes hold +0 and x+0==x.
            const int src = (int)__ffsll((long long)mm) - 1;
            float t = __shfl(acc[0], src, 64);
#pragma unroll
            for (int c = 1; c < 16; ++c) {
                float tc = __shfl(acc[c], src, 64);
                t = (lane == c) ? tc : t;
            }
            q   = t;
            dnm = fmaxf(__shfl(wsum, src, 64), 1e-6f);
        } else {
            // general path (rare): identical butterfly tree as prior rounds
#pragma unroll
            for (int s2 = 32; s2 >= 1; s2 >>= 1) {
                wsum += __shfl_xor(wsum, s2, 64);
#pragma unroll
                for (int c = 0; c < 16; ++c) acc[c] += __shfl_xor(acc[c], s2, 64);
            }
            float t = acc[0];
#pragma unroll
            for (int c2 = 1; c2 < 16; ++c2) t = (lane == c2) ? acc[c2] : t;
            q = t; dnm = fmaxf(wsum, 1e-6f);
        }

        q = q / dnm;                                   // ONE divide per lane
        const float p = __shfl(q, lane ^ 1, 64);       // x/y partner channel
        const float detc = (lane >= 16) ? bv
                         : (isx ? (q * m0 + p * m1 + m3) * wf
                                : (p * m4 + q * m5 + m7) * hf);

        if (stuck) {
            // det identical for all remaining rows; lane c holds det[c]
            if (lane < 17) sdet[lane] = detc;
            int n = (MAXD - iter) * 17;
            float* op = ob + iter * 17;
            int c = lane % 17;
            for (int e = lane; e < n; e += 64) {
                op[e] = sdet[c];
                c += 13; if (c >= 17) c -= 17;         // (e+64) % 17
            }
            break;
        } else {
            if (lane < 17) ob[iter * 17 + lane] = detc;
            ++iter;
            if (iter == MAXD) break;
        }
    }
}

// ONE WAVE per batch. Setup (loads, sigmoid, decode, compaction) identical to
// the proven R4/R5 kernel; R7's LDS aliasing reverted (it regressed).
__global__ __launch_bounds__(64, 2) void blaze_wave_kernel(
    const float* __restrict__ raw_boxes,   // [B,896,16]
    const float* __restrict__ raw_scores,  // [B,896]
    const float* __restrict__ anchors,     // [896,4]
    const float* __restrict__ tmat,        // [B,8]
    const int* __restrict__ hptr,
    const int* __restrict__ wptr,
    float* __restrict__ out,               // [B,64,17]
    int B)
{
    __shared__ float4 cbox[NANCH];            // compacted decoded boxes
    __shared__ float  cscore[NANCH];          // compacted scores
    __shared__ unsigned short cidx[NANCH];    // compacted -> original anchor idx
    __shared__ float  sdet[17];               // stuck-fill broadcast

    const int lane = threadIdx.x;             // 0..63
    const int b    = blockIdx.x;
    if (b >= B) return;

    const float* rb = raw_boxes  + (size_t)b * (NANCH * 16);
    const float* rs = raw_scores + (size_t)b * NANCH;
    const float inv = 1.f / 128.f;

    // ---- uniform per-batch params in the up-front load burst ----
    const float* M = tmat + (size_t)b * 8;
    const float m0 = M[0], m1 = M[1], m3 = M[3];
    const float m4 = M[4], m5 = M[5], m7 = M[7];
    const float hf = (float)(*hptr);
    const float wf = (float)(*wptr);

    // ---- Phase 1: ALL score loads issued back-to-back ----
    float xv[NS];
#pragma unroll
    for (int j = 0; j < NS; ++j) xv[j] = rs[lane + 64 * j];

    // ---- Phase 2: box/anchor loads gated by SIGN only (sigmoid>=0.5 <=> x>=0;
    //      NaN -> inactive both sides). Inactive lanes alias row 0's line. ----
    bool  act[NS];
    float4 r0v[NS], anv[NS];
#pragma unroll
    for (int j = 0; j < NS; ++j) {
        act[j] = (xv[j] >= 0.f);
        const int a2 = act[j] ? (lane + 64 * j) : 0;
        r0v[j] = *(const float4*)(rb + a2 * 16);
        anv[j] = *(const float4*)(anchors + a2 * 4);
    }

    // ---- sigmoid overlaps the in-flight box loads ----
    float sv[NS];
#pragma unroll
    for (int j = 0; j < NS; ++j) {
        float x = fminf(fmaxf(xv[j], -100.f), 100.f);
        sv[j] = 1.f / (1.f + expf(-x));
    }

    // ---- decode + COMPACT active anchors into LDS (ascending anchor order:
    //      compacted pos is order-isomorphic to anchor index -> exact tiebreak) ----
    int base = 0;
#pragma unroll
    for (int j = 0; j < NS; ++j) {
        float xc = r0v[j].x * inv * anv[j].z + anv[j].x;
        float yc = r0v[j].y * inv * anv[j].w + anv[j].y;
        float ww = r0v[j].z * inv * anv[j].z;
        float hh = r0v[j].w * inv * anv[j].w;
        float y0 = yc - hh * 0.5f, x0 = xc - ww * 0.5f;
        float y1 = yc + hh * 0.5f, x1 = xc + ww * 0.5f;
        unsigned long long m = __ballot(act[j]);
        int pos = base + __popcll(m & ((1ull << lane) - 1ull));
        if (act[j]) {
            cbox[pos]   = make_float4(y0, x0, y1, x1);
            cscore[pos] = sv[j];
            cidx[pos]   = (unsigned short)(lane + 64 * j);
        }
        base += __popcll(m);
    }
    const int nact = base;                  // wave-uniform
    const int nsc  = (nact + 63) >> 6;      // wave-uniform active slot count

    float* ob = out + (size_t)b * (MAXD * 17);

    // ---- one wave-uniform dispatch to a compile-time slot count ----
    if (nsc <= 7)
        nms_loop<7>(lane, nact, cbox, cscore, cidx, sdet, rb, anchors,
                    m0, m1, m3, m4, m5, m7, hf, wf, ob);
    else if (nsc <= 8)
        nms_loop<8>(lane, nact, cbox, cscore, cidx, sdet, rb, anchors,
                    m0, m1, m3, m4, m5, m7, hf, wf, ob);
    else if (nsc <= 10)
        nms_loop<10>(lane, nact, cbox, cscore, cidx, sdet, rb, anchors,
                     m0, m1, m3, m4, m5, m7, hf, wf, ob);
    else
        nms_loop<14>(lane, nact, cbox, cscore, cidx, sdet, rb, anchors,
                     m0, m1, m3, m4, m5, m7, hf, wf, ob);
}

extern "C" void kernel_launch(void* const* d_in, const int* in_sizes, int n_in,
                              void* d_out, int out_size, void* d_ws, size_t ws_size,
                              hipStream_t stream) {
    (void)n_in; (void)out_size; (void)d_ws; (void)ws_size;
    const float* raw_boxes  = (const float*)d_in[0];
    const float* raw_scores = (const float*)d_in[1];
    const float* anchors    = (const float*)d_in[2];
    const float* tmat       = (const float*)d_in[3];
    const int*   hptr       = (const int*)d_in[4];
    const int*   wptr       = (const int*)d_in[5];
    float* out = (float*)d_out;

    const int B = in_sizes[0] / (NANCH * 16);
    blaze_wave_kernel<<<B, 64, 0, stream>>>(raw_boxes, raw_scores, anchors,
                                            tmat, hptr, wptr, out, B);
}